// Round 10
// baseline (139.487 us; speedup 1.0000x reference)
//
#include <hip/hip_runtime.h>

#define NN 4
#define CC 64
#define GG 4
#define GCC 16
#define HH 128
#define WW 128
#define LL (HH*WW)
#define OMS 112        /* om row stride (floats); group g at col 28g, 27 used + pad */
#define WPC 192        /* packed col count: 64 v | 112 om (remapped) | 16 zero pad */

typedef __attribute__((ext_vector_type(8))) short bf16x8;   // 8 bf16 = 4 VGPR
typedef __attribute__((ext_vector_type(4))) float f32x4;    // MFMA 16x16x32 C/D

// bf16x3 split: v = hi + lo with |err| ~ 2^-18 |v|
static __device__ __forceinline__ unsigned short f2bf(float x) {
  union { float f; unsigned u; } v; v.f = x;
  unsigned r = v.u + 0x7fff + ((v.u >> 16) & 1);   // RNE
  return (unsigned short)(r >> 16);
}
static __device__ __forceinline__ float bf2f(unsigned short s) {
  union { float f; unsigned u; } v; v.u = ((unsigned)s) << 16; return v.f;
}
static __device__ __forceinline__ void split2(float x, unsigned short& h, unsigned short& l) {
  h = f2bf(x);
  l = f2bf(x - bf2f(h));
}

// ---------------------------------------------------------------------------
// Kernel 0: pack + bf16-split weights (unchanged from round 6).
// ---------------------------------------------------------------------------
__global__ void pack_kernel(const float* __restrict__ value_w, const float* __restrict__ value_b,
                            const float* __restrict__ om_w,    const float* __restrict__ om_b,
                            const float* __restrict__ out_w,
                            unsigned short* __restrict__ wphi, unsigned short* __restrict__ wplo,
                            unsigned short* __restrict__ owhi, unsigned short* __restrict__ owlo,
                            float* __restrict__ bpack)
{
  const int i = blockIdx.x * 256 + threadIdx.x;     // 48*256 = 12288 = WPC*64
  if (i < WPC * 64) {
    const int c = i >> 6, k = i & 63;
    float v = 0.0f;
    if (c < 64) v = value_w[c * 64 + k];
    else if (c < 176) {
      const int s = c - 64;
      if (s % 28 != 27) v = om_w[(s - s / 28) * 64 + k];
    }
    unsigned short h, l; split2(v, h, l);
    wphi[i] = h; wplo[i] = l;
  }
  if (i < 64 * 64) {
    unsigned short h, l; split2(out_w[i], h, l);
    owhi[i] = h; owlo[i] = l;
  }
  if (i < WPC) {
    float v = 0.0f;
    if (i < 64) v = value_b[i];
    else if (i < 176) { const int s = i - 64; if (s % 28 != 27) v = om_b[s - s / 28]; }
    bpack[i] = v;
  }
}

// ---------------------------------------------------------------------------
// Kernel 1: bf16x3 MFMA GEMM  inp @ [value_w|om_w].T  -> vws (GROUP-MAJOR) + omws
//   vws layout [n][g][pixel][16ch] so the dcn gather's pixel stride within
//   a group is 64B (was 256B) -> ~3-4x fewer L1 line-touches per gather load.
// ---------------------------------------------------------------------------
__global__ __launch_bounds__(256) void vm_kernel(
    const float* __restrict__ x,
    const unsigned short* __restrict__ wphi, const unsigned short* __restrict__ wplo,
    const float* __restrict__ bpack,
    float* __restrict__ vws, float* __restrict__ omws)
{
  __shared__ unsigned short ahi[128][72];   // 144B rows (9 quads, bank spread)
  __shared__ unsigned short alo[128][72];
  const int t   = threadIdx.x;
  const int sid = blockIdx.x;               // 0..511
  const int n   = sid >> 7;
  const int ll0 = (sid & 127) << 7;         // local pixel base within image
  const size_t gl0 = (size_t)sid << 7;      // global pixel base

  // stage + split x strip [64c][128px] -> ahi/alo[px][c]
  {
    const float* xb = x + (size_t)n * CC * LL + ll0;
    #pragma unroll
    for (int i = 0; i < 4; ++i) {
      const int pid = t + i * 256;          // 0..1023 = 32 c-pairs x 32 px-quads
      const int c   = (pid >> 5) << 1;
      const int px4 = (pid & 31) << 2;
      const float4 a = *(const float4*)(xb + (size_t)c * LL + px4);
      const float4 b = *(const float4*)(xb + (size_t)(c + 1) * LL + px4);
      const float av[4] = {a.x, a.y, a.z, a.w};
      const float bv[4] = {b.x, b.y, b.z, b.w};
      #pragma unroll
      for (int e = 0; e < 4; ++e) {
        unsigned short ha, la, hb, lb;
        split2(av[e], ha, la); split2(bv[e], hb, lb);
        *(unsigned*)&ahi[px4 + e][c] = (unsigned)ha | ((unsigned)hb << 16);
        *(unsigned*)&alo[px4 + e][c] = (unsigned)la | ((unsigned)lb << 16);
      }
    }
  }
  __syncthreads();

  const int w  = t >> 6;
  const int ln = t & 63;
  const int ct = blockIdx.y * 4 + w;        // col-tile 0..11 (11 = pad, not stored)
  const int c0 = ct << 4;
  const int r  = ln & 15;                   // A row / B col / D col
  const int kq = ln >> 4;                   // k-slice (operands) / row-group (D)

  bf16x8 Bh[2], Bl[2];
  #pragma unroll
  for (int ks = 0; ks < 2; ++ks) {
    Bh[ks] = *(const bf16x8*)&wphi[(c0 + r) * 64 + ks * 32 + kq * 8];
    Bl[ks] = *(const bf16x8*)&wplo[(c0 + r) * 64 + ks * 32 + kq * 8];
  }
  const float bias = bpack[c0 + r];

  #pragma unroll
  for (int pt = 0; pt < 8; ++pt) {
    bf16x8 Ah[2], Al[2];
    #pragma unroll
    for (int ks = 0; ks < 2; ++ks) {
      Ah[ks] = *(const bf16x8*)&ahi[pt * 16 + r][ks * 32 + kq * 8];
      Al[ks] = *(const bf16x8*)&alo[pt * 16 + r][ks * 32 + kq * 8];
    }
    f32x4 acc = {bias, bias, bias, bias};
    #pragma unroll
    for (int ks = 0; ks < 2; ++ks) {
      acc = __builtin_amdgcn_mfma_f32_16x16x32_bf16(Al[ks], Bh[ks], acc, 0, 0, 0);
      acc = __builtin_amdgcn_mfma_f32_16x16x32_bf16(Ah[ks], Bl[ks], acc, 0, 0, 0);
      acc = __builtin_amdgcn_mfma_f32_16x16x32_bf16(Ah[ks], Bh[ks], acc, 0, 0, 0);
    }
    // D: col = r, rows = kq*4 + j (consecutive pixels)
    if (ct < 4) {
      // group-major: [n][g=ct][pixel][16]
      float* d = vws + ((size_t)(n * GG + ct) * LL + ll0 + pt * 16 + kq * 4) * 16 + r;
      d[0] = acc[0]; d[16] = acc[1]; d[32] = acc[2]; d[48] = acc[3];
    } else if (ct < 11) {
      float* d = omws + (gl0 + pt * 16 + kq * 4) * (size_t)OMS + (c0 - 64) + r;
      d[0] = acc[0]; d[OMS] = acc[1]; d[2 * OMS] = acc[2]; d[3 * OMS] = acc[3];
    }
  }
}

// ---------------------------------------------------------------------------
// Kernel 2: gather (group-major v reads) + bf16x3 MFMA output GEMM + store.
//   phase A: (px,g,qq) one float4 per corner; within a wave the 4 px lanes'
//     segments are now 64B apart (same group) -> near-contiguous runs.
// ---------------------------------------------------------------------------
__global__ __launch_bounds__(512, 4) void dcn_kernel(
    const float* __restrict__ vws, const float* __restrict__ omws,
    const unsigned short* __restrict__ owhi, const unsigned short* __restrict__ owlo,
    const float* __restrict__ out_b,
    float* __restrict__ out)
{
  __shared__ unsigned short shi[32][72];
  __shared__ unsigned short slo[32][72];
  __shared__ float y_lds[32][68];
  const int t   = threadIdx.x;
  const int B   = blockIdx.x;               // 2048 blocks
  const int xcd = B & 7;
  const int n   = xcd >> 1;
  const int idx = ((xcd & 1) << 8) | (B >> 3);
  const int row = idx >> 2;
  const int l0  = (row << 7) + ((idx & 3) << 5);

  // ---- phase A: gather ----
  {
    const int px = t >> 4, g = (t >> 2) & 3, qq = t & 3;
    const int l  = l0 + px;
    const float pyf = (float)row;
    const float pxf = (float)(l & (WW - 1));
    const float* __restrict__ omp_  = omws + ((size_t)n * LL + l) * OMS + g * 28;
    const float* __restrict__ vbase = vws + (size_t)(n * GG + g) * LL * 16 + qq * 4;

    float buf[28];
    const float4* og4 = (const float4*)omp_;
    #pragma unroll
    for (int i = 0; i < 7; ++i) {
      const float4 vv = og4[i];
      buf[4*i+0] = vv.x; buf[4*i+1] = vv.y; buf[4*i+2] = vv.z; buf[4*i+3] = vv.w;
    }

    float s0 = 0.0f, s1 = 0.0f, s2 = 0.0f, s3 = 0.0f;
    #pragma unroll
    for (int pp = 0; pp < 9; ++pp) {
      const float sy  = pyf + (float)(pp / 3 - 1) + buf[2*pp+1];
      const float sx  = pxf + (float)(pp % 3 - 1) + buf[2*pp+0];
      const float y0f = floorf(sy), x0f = floorf(sx);
      const float wy  = sy - y0f,  wx  = sx - x0f;
      const int   iy  = (int)y0f,  ix  = (int)x0f;
      const float m   = buf[18 + pp];
      const float w00 = (1.0f - wy) * (1.0f - wx) * m;
      const float w01 = (1.0f - wy) * wx * m;
      const float w10 = wy * (1.0f - wx) * m;
      const float w11 = wy * wx * m;
      #pragma unroll
      for (int cor = 0; cor < 4; ++cor) {
        const int   cy = iy + (cor >> 1);
        const int   cx = ix + (cor & 1);
        const float wgt = (cor == 0) ? w00 : (cor == 1) ? w01 : (cor == 2) ? w10 : w11;
        if (cy >= 0 && cy < HH && cx >= 0 && cx < WW) {
          const float4 vv = *(const float4*)(vbase + (size_t)(cy * WW + cx) * 16);
          s0 = fmaf(wgt, vv.x, s0);
          s1 = fmaf(wgt, vv.y, s1);
          s2 = fmaf(wgt, vv.z, s2);
          s3 = fmaf(wgt, vv.w, s3);
        }
      }
    }
    unsigned short h0,u0,h1,u1,h2,u2,h3,u3;
    split2(s0,h0,u0); split2(s1,h1,u1); split2(s2,h2,u2); split2(s3,h3,u3);
    *(ushort4*)&shi[px][g * 16 + qq * 4] = make_ushort4(h0, h1, h2, h3);
    *(ushort4*)&slo[px][g * 16 + qq * 4] = make_ushort4(u0, u1, u2, u3);
  }
  __syncthreads();

  // ---- phase B: y = s @ out_w.T + out_b via bf16x3 MFMA ----
  {
    const int w  = t >> 6, ln = t & 63;
    const int pxt = w >> 2, ct = w & 3, c0 = ct << 4;
    const int r  = ln & 15, kq = ln >> 4;
    bf16x8 Ah[2], Al[2], Bh[2], Bl[2];
    #pragma unroll
    for (int ks = 0; ks < 2; ++ks) {
      Ah[ks] = *(const bf16x8*)&shi[pxt * 16 + r][ks * 32 + kq * 8];
      Al[ks] = *(const bf16x8*)&slo[pxt * 16 + r][ks * 32 + kq * 8];
      Bh[ks] = *(const bf16x8*)&owhi[(c0 + r) * 64 + ks * 32 + kq * 8];
      Bl[ks] = *(const bf16x8*)&owlo[(c0 + r) * 64 + ks * 32 + kq * 8];
    }
    const float bias = out_b[c0 + r];
    f32x4 acc = {bias, bias, bias, bias};
    #pragma unroll
    for (int ks = 0; ks < 2; ++ks) {
      acc = __builtin_amdgcn_mfma_f32_16x16x32_bf16(Al[ks], Bh[ks], acc, 0, 0, 0);
      acc = __builtin_amdgcn_mfma_f32_16x16x32_bf16(Ah[ks], Bl[ks], acc, 0, 0, 0);
      acc = __builtin_amdgcn_mfma_f32_16x16x32_bf16(Ah[ks], Bh[ks], acc, 0, 0, 0);
    }
    #pragma unroll
    for (int j = 0; j < 4; ++j)
      y_lds[pxt * 16 + kq * 4 + j][c0 + r] = acc[j];
  }
  __syncthreads();

  // ---- phase C: coalesced NCHW store ----
  {
    const int c = t >> 3, px4 = (t & 7) << 2;
    const float4 v = make_float4(y_lds[px4][c], y_lds[px4+1][c],
                                 y_lds[px4+2][c], y_lds[px4+3][c]);
    *(float4*)(out + ((size_t)n * CC + c) * LL + l0 + px4) = v;
  }
}

// ---------------------------------------------------------------------------
extern "C" void kernel_launch(void* const* d_in, const int* in_sizes, int n_in,
                              void* d_out, int out_size, void* d_ws, size_t ws_size,
                              hipStream_t stream) {
  const float* x       = (const float*)d_in[0];
  const float* value_w = (const float*)d_in[1];
  const float* value_b = (const float*)d_in[2];
  const float* om_w    = (const float*)d_in[3];
  const float* om_b    = (const float*)d_in[4];
  const float* out_w   = (const float*)d_in[5];
  const float* out_b   = (const float*)d_in[6];
  float* outp = (float*)d_out;

  float* vws   = (float*)d_ws;                        // 4*4*16384*16 f32 = 16.8 MB
  float* omws  = vws  + (size_t)NN * GG * LL * GCC;   // 4*16384*112  f32 = 29.4 MB
  float* bpack = omws + (size_t)NN * LL * OMS;        // 192 f32
  unsigned short* wphi = (unsigned short*)(bpack + WPC);
  unsigned short* wplo = wphi + WPC * 64;
  unsigned short* owhi = wplo + WPC * 64;
  unsigned short* owlo = owhi + 64 * 64;

  pack_kernel<<<dim3(48), dim3(256), 0, stream>>>(
      value_w, value_b, om_w, om_b, out_w, wphi, wplo, owhi, owlo, bpack);
  vm_kernel<<<dim3(512, 3), dim3(256), 0, stream>>>(
      x, wphi, wplo, bpack, vws, omws);
  dcn_kernel<<<dim3(2048), dim3(512), 0, stream>>>(
      vws, omws, owhi, owlo, out_b, outp);
}